// Round 6
// baseline (636.222 us; speedup 1.0000x reference)
//
#include <hip/hip_runtime.h>
#include <hip/hip_bf16.h>

typedef __attribute__((ext_vector_type(4))) float  f32x4;
typedef __attribute__((ext_vector_type(8))) short  bf16x8;
typedef unsigned short u16;

#define ALPHA 0.2f
#define NN 8192
#define FF 128
#define LOG2E 1.4426950408889634f

__device__ __forceinline__ u16 f2b(float f) {
  __hip_bfloat16 hb = __float2bfloat16(f);
  return *reinterpret_cast<u16*>(&hb);
}

// ---------- K0: convert x -> bf16 (xb), W -> bf16 transposed (WTb) ----------
extern "C" __global__ void __launch_bounds__(256)
wt_cvt(const float* __restrict__ x, const float* __restrict__ Wm,
       u16* __restrict__ xb, u16* __restrict__ WTb) {
  const int id = blockIdx.x * 256 + threadIdx.x;
  if (blockIdx.x < 2048) {                 // x: 2M elems, 4 per thread
    const f32x4 v = *(const f32x4*)(x + (size_t)id * 4);
    uint2 p;
    p.x = f2b(v.x) | ((unsigned)f2b(v.y) << 16);
    p.y = f2b(v.z) | ((unsigned)f2b(v.w) << 16);
    *(uint2*)(xb + (size_t)id * 4) = p;
  } else {                                  // WT: 32768 elems, 1 per thread
    const int o = id - 2048 * 256;          // o = c*256 + k
    const int c = o >> 8, k = o & 255;
    WTb[o] = f2b(Wm[k * 128 + c]);
  }
}

// ---------- K1: h = x@W via MFMA; write hT2 (fragment-tiled bf16), s1l, s2l --
// hT2 layout: elem(jblk, c, jw) at (jblk*128 + c)*32 + jw, jblk=j>>5, jw=j&31.
// A wave B-fragment (16 c-rows x 32 j) is then 1 KB fully contiguous.
extern "C" __global__ void __launch_bounds__(256)
gat_h(const u16* __restrict__ xb, const u16* __restrict__ WTb,
      const float* __restrict__ av, u16* __restrict__ hT2,
      float* __restrict__ s1v, float* __restrict__ s2v) {
  __shared__ float hs[16][128];
  const int t = threadIdx.x, lane = t & 63, wv = t >> 6;
  const int i0 = blockIdx.x * 16;
  const int fr = lane & 15, kg = lane >> 4;

  f32x4 acc0 = {0.f,0.f,0.f,0.f}, acc1 = {0.f,0.f,0.f,0.f};
  const u16* xp  = xb  + (size_t)(i0 + fr) * 256 + kg * 8;
  const u16* b0p = WTb + (size_t)(wv * 32 + fr) * 256 + kg * 8;
  const u16* b1p = b0p + 16 * 256;
#pragma unroll
  for (int ks = 0; ks < 8; ++ks) {
    const bf16x8 A  = *(const bf16x8*)(xp  + ks * 32);
    const bf16x8 B0 = *(const bf16x8*)(b0p + ks * 32);
    const bf16x8 B1 = *(const bf16x8*)(b1p + ks * 32);
    acc0 = __builtin_amdgcn_mfma_f32_16x16x32_bf16(A, B0, acc0, 0, 0, 0);
    acc1 = __builtin_amdgcn_mfma_f32_16x16x32_bf16(A, B1, acc1, 0, 0, 0);
  }
#pragma unroll
  for (int r = 0; r < 4; ++r) {            // C/D: row=(lane>>4)*4+r, col=lane&15
    hs[kg * 4 + r][wv * 32 + fr]      = acc0[r];
    hs[kg * 4 + r][wv * 32 + 16 + fr] = acc1[r];
  }
  __syncthreads();

  { // hT2 write: 16 nodes of this block = jw (i0&31)+0..15 of jblk i0>>5
    const int c = t >> 1, rr = (t & 1) * 8;
    u16 u[8];
#pragma unroll
    for (int m = 0; m < 8; ++m) u[m] = f2b(hs[rr + m][c]);
    *(uint4*)(hT2 + ((size_t)(i0 >> 5) * 128 + c) * 32 + (i0 & 31) + rr) =
        *(const uint4*)u;
  }
  { // s1/s2 (pre-scaled by log2e)
    const int r = t >> 4, q = t & 15;
    float p1 = 0.f, p2 = 0.f;
#pragma unroll
    for (int m = 0; m < 8; ++m) {
      const int c = q * 8 + m;
      const float hv = hs[r][c];
      p1 = fmaf(hv, av[c], p1);
      p2 = fmaf(hv, av[128 + c], p2);
    }
    p1 += __shfl_xor(p1, 1); p1 += __shfl_xor(p1, 2);
    p1 += __shfl_xor(p1, 4); p1 += __shfl_xor(p1, 8);
    p2 += __shfl_xor(p2, 1); p2 += __shfl_xor(p2, 2);
    p2 += __shfl_xor(p2, 4); p2 += __shfl_xor(p2, 8);
    if (q == 0) { s1v[i0 + r] = p1 * LOG2E; s2v[i0 + r] = p2 * LOG2E; }
  }
}

// ---------- K2: reg-only main loop, DISTANCE-2 adj prefetch -----------------
// 1024 blocks (256 tiles x 4 quarters) x 256 thr (4 waves), 3 blocks/CU.
// Wave ks owns k-slice j%128 in [ks*32,+32). adj prefetched 2 iterations
// ahead via ping-pong register sets (loop unrolled x2) -> ~2 full iters
// (>3000 cyc) of HBM-latency cover. z (s2, L2-hot) at distance-1.
#define MM(BB, AA) AA = __builtin_amdgcn_mfma_f32_16x16x32_bf16(af0, BB, AA, 0, 0, 0)
#define MM1(BB, AA) AA = __builtin_amdgcn_mfma_f32_16x16x32_bf16(af1, BB, AA, 0, 0, 0)

extern "C" __global__ void __launch_bounds__(256, 3)
gat_main(const float* __restrict__ adj, const u16* __restrict__ hT2,
         const float* __restrict__ s1l, const float* __restrict__ s2l,
         float* __restrict__ nump, float* __restrict__ deng) {
  __shared__ float accp[4][16][132];   // 33.8 KB
  __shared__ float denp[4][16];

  const int t = threadIdx.x, lane = t & 63, ks = t >> 6;
  const int fr = lane & 15, kg = lane >> 4;
  const int tile = blockIdx.x >> 2, q = blockIdx.x & 3;
  const int i0 = tile * 32;
  const int jq = q * 2048;

  const float s1i0 = s1l[i0 + fr];
  const float s1i1 = s1l[i0 + 16 + fr];
  const float* adjp0 = adj + (size_t)(i0 + fr) * NN + jq + ks * 32 + kg * 8;
  const float* adjp1 = adjp0 + (size_t)16 * NN;
  const float* s2p   = s2l + jq + ks * 32 + kg * 8;
  const u16*   hp    = hT2 + (size_t)(q * 64 + ks) * 4096 + fr * 32 + kg * 8;

  f32x4 acc0[8], acc1[8];
#pragma unroll
  for (int f = 0; f < 8; ++f) { acc0[f] = (f32x4){0,0,0,0}; acc1[f] = (f32x4){0,0,0,0}; }
  float den0 = 0.f, den1 = 0.f;

  // prologue: adj for it=0 (E) and it=1 (O); z for it=0
  f32x4 aE0 = *(const f32x4*)(adjp0);
  f32x4 aE1 = *(const f32x4*)(adjp0 + 4);
  f32x4 aE2 = *(const f32x4*)(adjp1);
  f32x4 aE3 = *(const f32x4*)(adjp1 + 4);
  f32x4 aO0 = *(const f32x4*)(adjp0 + 128);
  f32x4 aO1 = *(const f32x4*)(adjp0 + 132);
  f32x4 aO2 = *(const f32x4*)(adjp1 + 128);
  f32x4 aO3 = *(const f32x4*)(adjp1 + 132);
  f32x4 z0  = *(const f32x4*)(s2p);
  f32x4 z1  = *(const f32x4*)(s2p + 4);

  auto step = [&](f32x4& A0, f32x4& A1, f32x4& A2, f32x4& A3, int it) {
    const u16* hb = hp + it * 16384;
    const bf16x8 b0 = *(const bf16x8*)(hb);
    const bf16x8 b1 = *(const bf16x8*)(hb + 512);
    const bf16x8 b2 = *(const bf16x8*)(hb + 1024);
    const bf16x8 b3 = *(const bf16x8*)(hb + 1536);
    const bf16x8 b4 = *(const bf16x8*)(hb + 2048);
    const bf16x8 b5 = *(const bf16x8*)(hb + 2560);
    const bf16x8 b6 = *(const bf16x8*)(hb + 3072);
    const bf16x8 b7 = *(const bf16x8*)(hb + 3584);
    __builtin_amdgcn_sched_barrier(0);

    // A fragments for both row groups: w = adj * exp2(lrelu(s1l+s2l))
    bf16x8 af0, af1;
    float d0 = 0.f, d1 = 0.f;
#pragma unroll
    for (int e = 0; e < 8; ++e) {
      const float zz  = (e < 4) ? z0[e] : z1[e - 4];
      const float av0 = (e < 4) ? A0[e] : A1[e - 4];
      const float av1 = (e < 4) ? A2[e] : A3[e - 4];
      float t0 = s1i0 + zz; t0 = fmaxf(t0, ALPHA * t0);
      float t1 = s1i1 + zz; t1 = fmaxf(t1, ALPHA * t1);
      const float w0 = av0 * exp2f(t0);
      const float w1 = av1 * exp2f(t1);
      d0 += w0; d1 += w1;
      af0[e] = (short)f2b(w0);
      af1[e] = (short)f2b(w1);
    }
    den0 += d0; den1 += d1;
    __builtin_amdgcn_sched_barrier(0);

    // reload this parity's adj for it+2; z for it+1 (clamped, in-bounds)
    const int ia = it + 2 < 16 ? it + 2 : 15;
    const int iz = it + 1 < 16 ? it + 1 : 15;
    A0 = *(const f32x4*)(adjp0 + ia * 128);
    A1 = *(const f32x4*)(adjp0 + ia * 128 + 4);
    A2 = *(const f32x4*)(adjp1 + ia * 128);
    A3 = *(const f32x4*)(adjp1 + ia * 128 + 4);
    z0 = *(const f32x4*)(s2p + iz * 128);
    z1 = *(const f32x4*)(s2p + iz * 128 + 4);
    __builtin_amdgcn_sched_barrier(0);

    MM(b0, acc0[0]); MM1(b0, acc1[0]); MM(b1, acc0[1]); MM1(b1, acc1[1]);
    MM(b2, acc0[2]); MM1(b2, acc1[2]); MM(b3, acc0[3]); MM1(b3, acc1[3]);
    MM(b4, acc0[4]); MM1(b4, acc1[4]); MM(b5, acc0[5]); MM1(b5, acc1[5]);
    MM(b6, acc0[6]); MM1(b6, acc1[6]); MM(b7, acc0[7]); MM1(b7, acc1[7]);
  };

  for (int m = 0; m < 8; ++m) {
    step(aE0, aE1, aE2, aE3, 2 * m);
    step(aO0, aO1, aO2, aO3, 2 * m + 1);
  }

  const size_t obase = ((size_t)(q * 256 + tile)) * 32;

  // ---- pass 0: row group 0 (rows 0..15) ----
  {
    float d = den0;
    d += __shfl_xor(d, 16); d += __shfl_xor(d, 32);
    if (lane < 16) denp[ks][fr] = d;
#pragma unroll
    for (int f = 0; f < 8; ++f)
#pragma unroll
      for (int r = 0; r < 4; ++r) accp[ks][kg * 4 + r][f * 16 + fr] = acc0[f][r];
    __syncthreads();
    const int row = t >> 4, c0 = (t & 15) * 8;
    f32x4 sA = {0,0,0,0}, sB = {0,0,0,0};
#pragma unroll
    for (int w = 0; w < 4; ++w) {
      sA += *(const f32x4*)&accp[w][row][c0];
      sB += *(const f32x4*)&accp[w][row][c0 + 4];
    }
    float* op = nump + (obase + row) * FF + c0;
    *(f32x4*)op = sA; *(f32x4*)(op + 4) = sB;
    if ((t & 15) == 0)
      deng[obase + row] = denp[0][row] + denp[1][row] + denp[2][row] + denp[3][row];
    __syncthreads();
  }
  // ---- pass 1: row group 1 (rows 16..31) ----
  {
    float d = den1;
    d += __shfl_xor(d, 16); d += __shfl_xor(d, 32);
    if (lane < 16) denp[ks][fr] = d;
#pragma unroll
    for (int f = 0; f < 8; ++f)
#pragma unroll
      for (int r = 0; r < 4; ++r) accp[ks][kg * 4 + r][f * 16 + fr] = acc1[f][r];
    __syncthreads();
    const int row = t >> 4, c0 = (t & 15) * 8;
    f32x4 sA = {0,0,0,0}, sB = {0,0,0,0};
#pragma unroll
    for (int w = 0; w < 4; ++w) {
      sA += *(const f32x4*)&accp[w][row][c0];
      sB += *(const f32x4*)&accp[w][row][c0 + 4];
    }
    float* op = nump + (obase + 16 + row) * FF + c0;
    *(f32x4*)op = sA; *(f32x4*)(op + 4) = sB;
    if ((t & 15) == 0)
      deng[obase + 16 + row] = denp[0][row] + denp[1][row] + denp[2][row] + denp[3][row];
  }
}

// ---------- K3: 4-quarter reduce + softmax divide ---------------------------
extern "C" __global__ void __launch_bounds__(256)
gat_red(const float* __restrict__ nump, const float* __restrict__ deng,
        float* __restrict__ out) {
  const int gid = blockIdx.x * 256 + threadIdx.x;   // 262144 = 8192 * 32
  const int i = gid >> 5, c4 = (gid & 31) * 4;
  const int tile = i >> 5, row = i & 31;
  f32x4 s = {0,0,0,0};
  float dv = 0.f;
#pragma unroll
  for (int q = 0; q < 4; ++q) {
    const size_t rb = ((size_t)(q * 256 + tile)) * 32 + row;
    s  += *(const f32x4*)(nump + rb * FF + c4);
    dv += deng[rb];
  }
  const float inv = 1.f / dv;
  s *= inv;
  *(f32x4*)(out + (size_t)i * FF + c4) = s;
}

extern "C" void kernel_launch(void* const* d_in, const int* in_sizes, int n_in,
                              void* d_out, int out_size, void* d_ws, size_t ws_size,
                              hipStream_t stream) {
  const float* x   = (const float*)d_in[0];
  const float* adj = (const float*)d_in[1];
  const float* Wm  = (const float*)d_in[2];
  const float* av  = (const float*)d_in[3];
  float* out = (float*)d_out;

  char* ws = (char*)d_ws;
  u16*   hT2 = (u16*)(ws);                       // 2 MB
  float* s1v = (float*)(ws + 2097152);           // 32 KB
  float* s2v = (float*)(ws + 2129920);           // 32 KB
  u16*   xb  = (u16*)(ws + 2162688);             // 4 MB
  u16*   WTb = (u16*)(ws + 6356992);             // 64 KB
  float* nump = (float*)(ws + 6422528);          // 16.78 MB
  float* deng = (float*)(ws + 23199744);         // 128 KB

  wt_cvt  <<<2176, 256, 0, stream>>>(x, Wm, xb, WTb);
  gat_h   <<<NN / 16, 256, 0, stream>>>(xb, WTb, av, hT2, s1v, s2v);
  gat_main<<<1024, 256, 0, stream>>>(adj, hT2, s1v, s2v, nump, deng);
  gat_red <<<1024, 256, 0, stream>>>(nump, deng, out);
}

// Round 7
// 388.052 us; speedup vs baseline: 1.6395x; 1.6395x over previous
//
#include <hip/hip_runtime.h>
#include <hip/hip_bf16.h>

typedef __attribute__((ext_vector_type(4))) float  f32x4;
typedef __attribute__((ext_vector_type(8))) short  bf16x8;
typedef unsigned short u16;

#define ALPHA 0.2f
#define NN 8192
#define FF 128
#define LOG2E 1.4426950408889634f
#define AS1 __attribute__((address_space(1)))
#define AS3 __attribute__((address_space(3)))

__device__ __forceinline__ u16 f2b(float f) {
  __hip_bfloat16 hb = __float2bfloat16(f);
  return *reinterpret_cast<u16*>(&hb);
}

// ---------- K0: convert x -> bf16 (xb), W -> bf16 transposed (WTb) ----------
extern "C" __global__ void __launch_bounds__(256)
wt_cvt(const float* __restrict__ x, const float* __restrict__ Wm,
       u16* __restrict__ xb, u16* __restrict__ WTb) {
  const int id = blockIdx.x * 256 + threadIdx.x;
  if (blockIdx.x < 2048) {                 // x: 2M elems, 4 per thread
    const f32x4 v = *(const f32x4*)(x + (size_t)id * 4);
    uint2 p;
    p.x = f2b(v.x) | ((unsigned)f2b(v.y) << 16);
    p.y = f2b(v.z) | ((unsigned)f2b(v.w) << 16);
    *(uint2*)(xb + (size_t)id * 4) = p;
  } else {                                  // WT: 32768 elems, 1 per thread
    const int o = id - 2048 * 256;          // o = c*256 + k
    const int c = o >> 8, k = o & 255;
    WTb[o] = f2b(Wm[k * 128 + c]);
  }
}

// ---------- K1: h = x@W via MFMA; write hT2 (fragment-tiled bf16), s1l, s2l --
// hT2 layout: elem(jblk, c, jw) at (jblk*128 + c)*32 + jw, jblk=j>>5, jw=j&31.
// A wave B-fragment (16 c-rows x 32 j) is then 1 KB fully contiguous.
extern "C" __global__ void __launch_bounds__(256)
gat_h(const u16* __restrict__ xb, const u16* __restrict__ WTb,
      const float* __restrict__ av, u16* __restrict__ hT2,
      float* __restrict__ s1v, float* __restrict__ s2v) {
  __shared__ float hs[16][128];
  const int t = threadIdx.x, lane = t & 63, wv = t >> 6;
  const int i0 = blockIdx.x * 16;
  const int fr = lane & 15, kg = lane >> 4;

  f32x4 acc0 = {0.f,0.f,0.f,0.f}, acc1 = {0.f,0.f,0.f,0.f};
  const u16* xp  = xb  + (size_t)(i0 + fr) * 256 + kg * 8;
  const u16* b0p = WTb + (size_t)(wv * 32 + fr) * 256 + kg * 8;
  const u16* b1p = b0p + 16 * 256;
#pragma unroll
  for (int ks = 0; ks < 8; ++ks) {
    const bf16x8 A  = *(const bf16x8*)(xp  + ks * 32);
    const bf16x8 B0 = *(const bf16x8*)(b0p + ks * 32);
    const bf16x8 B1 = *(const bf16x8*)(b1p + ks * 32);
    acc0 = __builtin_amdgcn_mfma_f32_16x16x32_bf16(A, B0, acc0, 0, 0, 0);
    acc1 = __builtin_amdgcn_mfma_f32_16x16x32_bf16(A, B1, acc1, 0, 0, 0);
  }
#pragma unroll
  for (int r = 0; r < 4; ++r) {            // C/D: row=(lane>>4)*4+r, col=lane&15
    hs[kg * 4 + r][wv * 32 + fr]      = acc0[r];
    hs[kg * 4 + r][wv * 32 + 16 + fr] = acc1[r];
  }
  __syncthreads();

  { // hT2 write: 16 nodes of this block = jw (i0&31)+0..15 of jblk i0>>5
    const int c = t >> 1, rr = (t & 1) * 8;
    u16 u[8];
#pragma unroll
    for (int m = 0; m < 8; ++m) u[m] = f2b(hs[rr + m][c]);
    *(uint4*)(hT2 + ((size_t)(i0 >> 5) * 128 + c) * 32 + (i0 & 31) + rr) =
        *(const uint4*)u;
  }
  { // s1/s2 (pre-scaled by log2e)
    const int r = t >> 4, q = t & 15;
    float p1 = 0.f, p2 = 0.f;
#pragma unroll
    for (int m = 0; m < 8; ++m) {
      const int c = q * 8 + m;
      const float hv = hs[r][c];
      p1 = fmaf(hv, av[c], p1);
      p2 = fmaf(hv, av[128 + c], p2);
    }
    p1 += __shfl_xor(p1, 1); p1 += __shfl_xor(p1, 2);
    p1 += __shfl_xor(p1, 4); p1 += __shfl_xor(p1, 8);
    p2 += __shfl_xor(p2, 1); p2 += __shfl_xor(p2, 2);
    p2 += __shfl_xor(p2, 4); p2 += __shfl_xor(p2, 8);
    if (q == 0) { s1v[i0 + r] = p1 * LOG2E; s2v[i0 + r] = p2 * LOG2E; }
  }
}

// ---------- K2: adj via global_load_lds ring (depth-1, m97 pattern) ---------
// 1024 blocks (256 tiles x 4 quarters) x 256 thr (4 waves), (256,3).
// adj tile 32x128 f32 = 16 KB staged by DMA into a 2-buffer LDS ring; no adj
// registers at all. Wave ks owns k-slice j%128 in [ks*32,+32); A-fragments
// built from LDS adj + exp; B-frags from L2-resident hT2. Epilogue accp
// overlays the adj ring.
#define MM(BB, AA) AA = __builtin_amdgcn_mfma_f32_16x16x32_bf16(af0, BB, AA, 0, 0, 0)
#define MM1(BB, AA) AA = __builtin_amdgcn_mfma_f32_16x16x32_bf16(af1, BB, AA, 0, 0, 0)

extern "C" __global__ void __launch_bounds__(256, 3)
gat_main(const float* __restrict__ adj, const u16* __restrict__ hT2,
         const float* __restrict__ s1l, const float* __restrict__ s2l,
         float* __restrict__ nump, float* __restrict__ deng) {
  __shared__ __align__(16) char pool[34048];  // 2x16KB adj ring; epilogue overlay

  const int t = threadIdx.x, lane = t & 63, ks = t >> 6;
  const int fr = lane & 15, kg = lane >> 4;
  const int tile = blockIdx.x >> 2, q = blockIdx.x & 3;
  const int i0 = tile * 32;
  const int jq = q * 2048;

  const float s1i0 = s1l[i0 + fr];
  const float s1i1 = s1l[i0 + 16 + fr];
  const float* s2p = s2l + jq + ks * 32 + kg * 8;
  const u16*   hp  = hT2 + (size_t)(q * 64 + ks) * 4096 + fr * 32 + kg * 8;

  // DMA source: wave ks stages rows ks*8..+7. Instr d covers rows ks*8+2d,+1;
  // lane l -> row += (l>>5), col = (l&31)*4 floats (16 B). LDS dest linear.
  const int drow = ks * 8 + (lane >> 5);
  const float* gp0 = adj + (size_t)(i0 + drow + 0) * NN + jq + (lane & 31) * 4;
  const float* gp2 = gp0 + (size_t)2 * NN;
  const float* gp4 = gp0 + (size_t)4 * NN;
  const float* gp6 = gp0 + (size_t)6 * NN;

  f32x4 acc0[8], acc1[8];
#pragma unroll
  for (int f = 0; f < 8; ++f) { acc0[f] = (f32x4){0,0,0,0}; acc1[f] = (f32x4){0,0,0,0}; }
  float den0 = 0.f, den1 = 0.f;

  auto STAGE = [&](int buf, int tt) {
    char* lb = pool + buf * 16384 + ks * 4096;
    const size_t off = (size_t)tt * 128;
    __builtin_amdgcn_global_load_lds((const AS1 void*)(gp0 + off), (AS3 void*)(lb       ), 16, 0, 0);
    __builtin_amdgcn_global_load_lds((const AS1 void*)(gp2 + off), (AS3 void*)(lb + 1024), 16, 0, 0);
    __builtin_amdgcn_global_load_lds((const AS1 void*)(gp4 + off), (AS3 void*)(lb + 2048), 16, 0, 0);
    __builtin_amdgcn_global_load_lds((const AS1 void*)(gp6 + off), (AS3 void*)(lb + 3072), 16, 0, 0);
    __builtin_amdgcn_sched_barrier(0);   // issue DMAs before anything later
  };

  auto COMPUTE = [&](int buf, int tt) {
    // z for this tile (L2-hot)
    const f32x4 z0 = *(const f32x4*)(s2p + tt * 128);
    const f32x4 z1 = *(const f32x4*)(s2p + tt * 128 + 4);
    // B fragments (L2-resident hT2), batch-issued
    const u16* hb = hp + (size_t)tt * 16384;
    const bf16x8 b0 = *(const bf16x8*)(hb);
    const bf16x8 b1 = *(const bf16x8*)(hb + 512);
    const bf16x8 b2 = *(const bf16x8*)(hb + 1024);
    const bf16x8 b3 = *(const bf16x8*)(hb + 1536);
    const bf16x8 b4 = *(const bf16x8*)(hb + 2048);
    const bf16x8 b5 = *(const bf16x8*)(hb + 2560);
    const bf16x8 b6 = *(const bf16x8*)(hb + 3072);
    const bf16x8 b7 = *(const bf16x8*)(hb + 3584);
    // adj from LDS: rows fr and fr+16, cols ks*32+kg*8..+8
    const char* ab = pool + buf * 16384;
    const int cb = ks * 128 + kg * 32;
    const f32x4 x0 = *(const f32x4*)(ab + fr * 512 + cb);
    const f32x4 x1 = *(const f32x4*)(ab + fr * 512 + cb + 16);
    const f32x4 x2 = *(const f32x4*)(ab + (16 + fr) * 512 + cb);
    const f32x4 x3 = *(const f32x4*)(ab + (16 + fr) * 512 + cb + 16);
    __builtin_amdgcn_sched_barrier(0);   // all loads issued before exp block

    bf16x8 af0, af1;
    float d0 = 0.f, d1 = 0.f;
#pragma unroll
    for (int e = 0; e < 8; ++e) {
      const float zz  = (e < 4) ? z0[e] : z1[e - 4];
      const float av0 = (e < 4) ? x0[e] : x1[e - 4];
      const float av1 = (e < 4) ? x2[e] : x3[e - 4];
      float t0 = s1i0 + zz; t0 = fmaxf(t0, ALPHA * t0);
      float t1 = s1i1 + zz; t1 = fmaxf(t1, ALPHA * t1);
      const float w0 = av0 * exp2f(t0);
      const float w1 = av1 * exp2f(t1);
      d0 += w0; d1 += w1;
      af0[e] = (short)f2b(w0);
      af1[e] = (short)f2b(w1);
    }
    den0 += d0; den1 += d1;

    MM(b0, acc0[0]); MM1(b0, acc1[0]); MM(b1, acc0[1]); MM1(b1, acc1[1]);
    MM(b2, acc0[2]); MM1(b2, acc1[2]); MM(b3, acc0[3]); MM1(b3, acc1[3]);
    MM(b4, acc0[4]); MM1(b4, acc1[4]); MM(b5, acc0[5]); MM1(b5, acc1[5]);
    MM(b6, acc0[6]); MM1(b6, acc1[6]); MM(b7, acc0[7]); MM1(b7, acc1[7]);
  };

  // prologue: tile 0 staged and drained
  STAGE(0, 0);
  __syncthreads();
  // main loop: stage t+1, compute t, drain (syncthreads implies vmcnt(0))
  for (int tt = 0; tt < 15; ++tt) {
    STAGE((tt + 1) & 1, tt + 1);
    COMPUTE(tt & 1, tt);
    __syncthreads();
  }
  COMPUTE(1, 15);
  __syncthreads();                     // adj ring dead; pool becomes accp/denp

  float (*accp)[16][132] = (float (*)[16][132])(void*)pool;   // 33792 B
  float* denp = (float*)(pool + 33792);                       // [4][16]

  const size_t obase = ((size_t)(q * 256 + tile)) * 32;

  // ---- pass 0: row group 0 (rows 0..15) ----
  {
    float d = den0;
    d += __shfl_xor(d, 16); d += __shfl_xor(d, 32);
    if (lane < 16) denp[ks * 16 + fr] = d;
#pragma unroll
    for (int f = 0; f < 8; ++f)
#pragma unroll
      for (int r = 0; r < 4; ++r) accp[ks][kg * 4 + r][f * 16 + fr] = acc0[f][r];
    __syncthreads();
    const int row = t >> 4, c0 = (t & 15) * 8;
    f32x4 sA = {0,0,0,0}, sB = {0,0,0,0};
#pragma unroll
    for (int w = 0; w < 4; ++w) {
      sA += *(const f32x4*)&accp[w][row][c0];
      sB += *(const f32x4*)&accp[w][row][c0 + 4];
    }
    float* op = nump + (obase + row) * FF + c0;
    *(f32x4*)op = sA; *(f32x4*)(op + 4) = sB;
    if ((t & 15) == 0)
      deng[obase + row] = denp[row] + denp[16 + row] + denp[32 + row] + denp[48 + row];
    __syncthreads();
  }
  // ---- pass 1: row group 1 (rows 16..31) ----
  {
    float d = den1;
    d += __shfl_xor(d, 16); d += __shfl_xor(d, 32);
    if (lane < 16) denp[ks * 16 + fr] = d;
#pragma unroll
    for (int f = 0; f < 8; ++f)
#pragma unroll
      for (int r = 0; r < 4; ++r) accp[ks][kg * 4 + r][f * 16 + fr] = acc1[f][r];
    __syncthreads();
    const int row = t >> 4, c0 = (t & 15) * 8;
    f32x4 sA = {0,0,0,0}, sB = {0,0,0,0};
#pragma unroll
    for (int w = 0; w < 4; ++w) {
      sA += *(const f32x4*)&accp[w][row][c0];
      sB += *(const f32x4*)&accp[w][row][c0 + 4];
    }
    float* op = nump + (obase + 16 + row) * FF + c0;
    *(f32x4*)op = sA; *(f32x4*)(op + 4) = sB;
    if ((t & 15) == 0)
      deng[obase + 16 + row] = denp[row] + denp[16 + row] + denp[32 + row] + denp[48 + row];
  }
}

// ---------- K3: 4-quarter reduce + softmax divide ---------------------------
extern "C" __global__ void __launch_bounds__(256)
gat_red(const float* __restrict__ nump, const float* __restrict__ deng,
        float* __restrict__ out) {
  const int gid = blockIdx.x * 256 + threadIdx.x;   // 262144 = 8192 * 32
  const int i = gid >> 5, c4 = (gid & 31) * 4;
  const int tile = i >> 5, row = i & 31;
  f32x4 s = {0,0,0,0};
  float dv = 0.f;
#pragma unroll
  for (int q = 0; q < 4; ++q) {
    const size_t rb = ((size_t)(q * 256 + tile)) * 32 + row;
    s  += *(const f32x4*)(nump + rb * FF + c4);
    dv += deng[rb];
  }
  const float inv = 1.f / dv;
  s *= inv;
  *(f32x4*)(out + (size_t)i * FF + c4) = s;
}

extern "C" void kernel_launch(void* const* d_in, const int* in_sizes, int n_in,
                              void* d_out, int out_size, void* d_ws, size_t ws_size,
                              hipStream_t stream) {
  const float* x   = (const float*)d_in[0];
  const float* adj = (const float*)d_in[1];
  const float* Wm  = (const float*)d_in[2];
  const float* av  = (const float*)d_in[3];
  float* out = (float*)d_out;

  char* ws = (char*)d_ws;
  u16*   hT2 = (u16*)(ws);                       // 2 MB
  float* s1v = (float*)(ws + 2097152);           // 32 KB
  float* s2v = (float*)(ws + 2129920);           // 32 KB
  u16*   xb  = (u16*)(ws + 2162688);             // 4 MB
  u16*   WTb = (u16*)(ws + 6356992);             // 64 KB
  float* nump = (float*)(ws + 6422528);          // 16.78 MB
  float* deng = (float*)(ws + 23199744);         // 128 KB

  wt_cvt  <<<2176, 256, 0, stream>>>(x, Wm, xb, WTb);
  gat_h   <<<NN / 16, 256, 0, stream>>>(xb, WTb, av, hT2, s1v, s2v);
  gat_main<<<1024, 256, 0, stream>>>(adj, hT2, s1v, s2v, nump, deng);
  gat_red <<<1024, 256, 0, stream>>>(nump, deng, out);
}